// Round 15
// baseline (61.239 us; speedup 1.0000x reference)
//
#include <hip/hip_runtime.h>

#define NB    4
#define NPB   8192
#define NPTS  (NB*NPB)      // 32768
#define KNB   32
#define CH    64
#define W1C   67
#define EPSV  1e-5f
#define SLOPEV 0.1f

typedef float f32x2 __attribute__((ext_vector_type(2)));
typedef float f32x4 __attribute__((ext_vector_type(4)));
typedef short bf16x8 __attribute__((ext_vector_type(8)));
typedef unsigned short u16;
typedef u16 u16x4 __attribute__((ext_vector_type(4)));
typedef u16 u16x8 __attribute__((ext_vector_type(8)));

// workspace layout (float offsets) — all big buffers bf16
#define WS_STATS1 0
#define WS_STATS2 64
#define WS_STATS3 128
#define WS_YB     256                        // bf16 Y, later bf16 z2pre
#define WS_MX     (WS_YB + NPTS*CH/2)        // bf16 Mx, later bf16 z3pre
#define WS_MN     (WS_MX + NPTS*CH/2)        // bf16 Mn

#define LDPW 68                // Wl row stride (u16): 4-way max alias
#define SEDS (KNB*4 + 4)       // per-point float stride in sed
#define EPB  32                // edge points per block (4 pts/wave, 8 waves)

__device__ __forceinline__ u16 f2bf(float f) {
    unsigned u = __float_as_uint(f);
    u += 0x7fff + ((u >> 16) & 1);          // round-nearest-even
    return (u16)(u >> 16);
}
__device__ __forceinline__ float bf2f(u16 h) {
    return __uint_as_float(((unsigned)h) << 16);
}
__device__ __forceinline__ bool probe_is32(const int* e_i32, int tid) {
    int found = 0;
    #pragma unroll
    for (int i = 0; i < 8; ++i)
        found |= (e_i32[(tid*8 + i)*2 + 1] != 0);
    return (__ballot(found) != 0ull);
}

// ---------------------------------------------------------------- MFMA matmul family (64 pts/block)
// MODE 0: YB(bf16) = sig * W1s^T   (+ stats zeroing in block 0)
// MODE 1: Z2B(bf16) = GN1(lrelu,max/min-select) * W2^T; stats2
// MODE 2: Z3B(bf16) = GN2(lrelu) * W3^T; stats3
template<int MODE>
__global__ __launch_bounds__(256) void k_mm(
    const void* __restrict__ X0, const void* __restrict__ X1,
    const float* __restrict__ Wg,
    const float* __restrict__ statsIn, float invcnt,
    const float* __restrict__ gm, const float* __restrict__ bt,
    u16* __restrict__ Out, float* __restrict__ statsOut,
    float* __restrict__ zeroStats)
{
    __shared__ u16 Wl[64*LDPW];
    __shared__ __align__(16) float affA[64];
    __shared__ __align__(16) float affB[64];
    __shared__ float lacc[16];
    int tid = threadIdx.x;
    int pbase = blockIdx.x * 64;
    int b = pbase >> 13;

    if (MODE == 0 && blockIdx.x == 0 && tid < 192) zeroStats[tid] = 0.f;
    if (MODE != 0) {
        if (tid < 64) {
            int g = tid >> 3;
            float sv = statsIn[b*16 + g*2 + 0];
            float qv = statsIn[b*16 + g*2 + 1];
            float mean = sv * invcnt;
            float var  = fmaf(-mean, mean, qv * invcnt);
            float rstd = rsqrtf(var + EPSV);
            float a = gm[tid] * rstd;
            affA[tid] = a;
            affB[tid] = fmaf(-mean, a, bt[tid]);
        }
        if (tid < 16) lacc[tid] = 0.f;
    }
    {
        const int wstride = (MODE == 0) ? W1C : 64;
        #pragma unroll
        for (int i = 0; i < 16; ++i) {
            int e = tid + 256*i;
            int o = e >> 6, m = e & 63;
            Wl[o*LDPW + m] = f2bf(Wg[o*wstride + m]);
        }
    }
    __syncthreads();

    int l = tid & 63, w = tid >> 6;
    int lr = l & 15, lk = l >> 4;
    int row = pbase + w*16 + lr;

    bf16x8 af[2];
    #pragma unroll
    for (int kh = 0; kh < 2; ++kh) {
        int m0 = kh*32 + lk*8;
        bf16x8 h;
        if (MODE == 0) {
            f32x4 a0 = *(const f32x4*)&((const float*)X0)[row*64 + m0];
            f32x4 a1 = *(const f32x4*)&((const float*)X0)[row*64 + m0 + 4];
            #pragma unroll
            for (int j = 0; j < 4; ++j) {
                h[j]   = (short)f2bf(a0[j]);
                h[4+j] = (short)f2bf(a1[j]);
            }
        } else {
            float aA[8], aB[8];
            *(f32x4*)&aA[0] = *(const f32x4*)&affA[m0];
            *(f32x4*)&aA[4] = *(const f32x4*)&affA[m0+4];
            *(f32x4*)&aB[0] = *(const f32x4*)&affB[m0];
            *(f32x4*)&aB[4] = *(const f32x4*)&affB[m0+4];
            u16x8 vx = *(const u16x8*)&((const u16*)X0)[row*64 + m0];
            if (MODE == 1) {
                u16x8 vn = *(const u16x8*)&((const u16*)X1)[row*64 + m0];
                #pragma unroll
                for (int j = 0; j < 8; ++j) {
                    float a = aA[j];
                    float x = (a < 0.f) ? bf2f(vn[j]) : bf2f(vx[j]);
                    float z = fmaf(a, x, aB[j]);
                    z = (z >= 0.f) ? z : SLOPEV * z;
                    h[j] = (short)f2bf(z);
                }
            } else {
                #pragma unroll
                for (int j = 0; j < 8; ++j) {
                    float z = fmaf(aA[j], bf2f(vx[j]), aB[j]);
                    z = (z >= 0.f) ? z : SLOPEV * z;
                    h[j] = (short)f2bf(z);
                }
            }
        }
        af[kh] = h;
    }

    bf16x8 bw[4][2];
    #pragma unroll
    for (int ot = 0; ot < 4; ++ot)
        #pragma unroll
        for (int kh = 0; kh < 2; ++kh)
            bw[ot][kh] = *(const bf16x8*)&Wl[(ot*16 + lr)*LDPW + kh*32 + lk*8];

    f32x4 acc[4];
    #pragma unroll
    for (int ot = 0; ot < 4; ++ot) {
        f32x4 c = {0.f, 0.f, 0.f, 0.f};
        c = __builtin_amdgcn_mfma_f32_16x16x32_bf16(af[0], bw[ot][0], c, 0, 0, 0);
        c = __builtin_amdgcn_mfma_f32_16x16x32_bf16(af[1], bw[ot][1], c, 0, 0, 0);
        acc[ot] = c;
    }

    #pragma unroll
    for (int ot = 0; ot < 4; ++ot)
        #pragma unroll
        for (int r = 0; r < 4; ++r) {
            int p = pbase + w*16 + lk*4 + r;
            int o = ot*16 + lr;
            Out[p*64 + o] = f2bf(acc[ot][r]);
        }

    if (MODE != 0) {
        #pragma unroll
        for (int ot = 0; ot < 4; ++ot) {
            float s = 0.f, ss = 0.f;
            #pragma unroll
            for (int r = 0; r < 4; ++r) {
                float v = acc[ot][r];
                s += v;
                ss = fmaf(v, v, ss);
            }
            s += __shfl_xor(s, 16, 64);  ss += __shfl_xor(ss, 16, 64);
            s += __shfl_xor(s, 32, 64);  ss += __shfl_xor(ss, 32, 64);
            s += __shfl_xor(s, 1, 64);   ss += __shfl_xor(ss, 1, 64);
            s += __shfl_xor(s, 2, 64);   ss += __shfl_xor(ss, 2, 64);
            s += __shfl_xor(s, 4, 64);   ss += __shfl_xor(ss, 4, 64);
            if ((l & 7) == 0 && l < 16) {
                int g = ot*2 + (l >> 3);
                atomicAdd(&lacc[g*2 + 0], s);
                atomicAdd(&lacc[g*2 + 1], ss);
            }
        }
        __syncthreads();
        if (tid < 16)
            atomicAdd(&statsOut[b*16 + tid], lacc[tid]);
    }
}

// ---------------------------------------------------------------- edge pass
// 512 thr, 32 pts/block, 4 pts/wave (16 lanes/pt), 2-stage SW pipeline
__global__ __launch_bounds__(512) void k_edge(
    const u16* __restrict__ Yb, const void* __restrict__ edg,
    const float* __restrict__ ef, const float* __restrict__ W1,
    u16* __restrict__ Mx, u16* __restrict__ Mn, float* __restrict__ stats1)
{
    __shared__ float sed[EPB*SEDS];           // 16896 B
    __shared__ float lacc[16];
    int tid = threadIdx.x;
    if (tid < 16) lacc[tid] = 0.f;

    bool is32 = probe_is32((const int*)edg, tid);
    {
        const int* e32 = (const int*)edg;
        const long long* e64 = (const long long*)edg;
        int ebase = blockIdx.x * (EPB*KNB);
        #pragma unroll
        for (int i = 0; i < 2; ++i) {
            int idx = tid + i*512;            // 0..1023 = pt*KNB + k
            int gi  = ebase + idx;
            int e   = is32 ? __builtin_nontemporal_load(e32 + gi)
                           : (int)__builtin_nontemporal_load(e64 + gi);
            int pt = idx >> 5, k = idx & 31;
            float* d = &sed[pt*SEDS + k*4];
            d[0] = __builtin_nontemporal_load(ef + gi*3 + 0);
            d[1] = __builtin_nontemporal_load(ef + gi*3 + 1);
            d[2] = __builtin_nontemporal_load(ef + gi*3 + 2);
            d[3] = __int_as_float(e << 7);
        }
    }

    int lane = tid & 63, wv = tid >> 6;       // 8 waves
    int il = lane & 15;                       // channel quad: ch il*4..il*4+3
    int g4 = lane >> 4;                       // point slot 0..3
    int lpt = wv*4 + g4;                      // local point 0..31
    int p = blockIdx.x * EPB + lpt;

    f32x2 w0[2], w1[2], w2[2], yp[2], mx[2], mn[2];
    #pragma unroll
    for (int jj = 0; jj < 2; ++jj) {
        int ch = il*4 + jj*2;
        w0[jj] = (f32x2){W1[ch*W1C + 64], W1[(ch+1)*W1C + 64]};
        w1[jj] = (f32x2){W1[ch*W1C + 65], W1[(ch+1)*W1C + 65]};
        w2[jj] = (f32x2){W1[ch*W1C + 66], W1[(ch+1)*W1C + 66]};
    }
    u16x4 yh = *(const u16x4*)&Yb[p*64 + il*4];
    #pragma unroll
    for (int jj = 0; jj < 2; ++jj) {
        yp[jj] = (f32x2){bf2f(yh[jj*2]), bf2f(yh[jj*2+1])};
        mx[jj] = (f32x2){-3.4e38f, -3.4e38f};
        mn[jj] = (f32x2){ 3.4e38f,  3.4e38f};
    }
    f32x2 s2 = {0.f, 0.f}, ss2 = {0.f, 0.f};
    __syncthreads();

    const char* Ybase = (const char*)Yb + il*8;
    const float* sp = &sed[lpt*SEDS];

    // 2-stage software pipeline
    f32x4 m4 = *(const f32x4*)(sp);
    u16x4 q = *(const u16x4*)(Ybase + __float_as_int(m4[3]));
    #pragma unroll 4
    for (int k = 0; k < KNB; ++k) {
        f32x4 m4n;
        u16x4 qn;
        if (k < KNB-1) {
            m4n = *(const f32x4*)(sp + (k+1)*4);
            qn  = *(const u16x4*)(Ybase + __float_as_int(m4n[3]));
        }
        f32x2 c0v = m4[0], c1v = m4[1], c2v = m4[2];
        #pragma unroll
        for (int jj = 0; jj < 2; ++jj) {
            f32x2 qq = {bf2f(q[jj*2]), bf2f(q[jj*2+1])};
            f32x2 t = qq - yp[jj];
            t = __builtin_elementwise_fma(c0v, w0[jj], t);
            t = __builtin_elementwise_fma(c1v, w1[jj], t);
            t = __builtin_elementwise_fma(c2v, w2[jj], t);
            mx[jj] = __builtin_elementwise_max(mx[jj], t);
            mn[jj] = __builtin_elementwise_min(mn[jj], t);
            s2 += t;
            ss2 = __builtin_elementwise_fma(t, t, ss2);
        }
        m4 = m4n;
        q  = qn;
    }

    u16x4 hx, hn;
    #pragma unroll
    for (int jj = 0; jj < 2; ++jj) {
        hx[jj*2] = f2bf(mx[jj].x); hx[jj*2+1] = f2bf(mx[jj].y);
        hn[jj*2] = f2bf(mn[jj].x); hn[jj*2+1] = f2bf(mn[jj].y);
    }
    __builtin_nontemporal_store(hx, (u16x4*)(Mx + p*64 + il*4));
    __builtin_nontemporal_store(hn, (u16x4*)(Mn + p*64 + il*4));

    // lane covers half of GN group (il>>1); reduce over lane bits {0,4,5}
    float s  = s2.x + s2.y;
    float ss = ss2.x + ss2.y;
    s += __shfl_xor(s,  1, 64);  ss += __shfl_xor(ss,  1, 64);
    s += __shfl_xor(s, 16, 64);  ss += __shfl_xor(ss, 16, 64);
    s += __shfl_xor(s, 32, 64);  ss += __shfl_xor(ss, 32, 64);
    if ((lane & 0x31) == 0) {                 // lanes 0,2,4,...,14
        int g = (lane >> 1) & 7;
        atomicAdd(&lacc[g*2 + 0], s);
        atomicAdd(&lacc[g*2 + 1], ss);
    }
    __syncthreads();
    if (tid < 16) {
        int b = (blockIdx.x * EPB) >> 13;
        atomicAdd(&stats1[b*16 + tid], lacc[tid]);
    }
}

// ---------------------------------------------------------------- final GN + lrelu -> out (64 pts/block)
__global__ __launch_bounds__(256) void k_out(
    const u16* __restrict__ z3, const float* __restrict__ stats,
    const float* __restrict__ g3, const float* __restrict__ b3,
    float* __restrict__ out)
{
    const float invcnt = 1.f/(float)(NPB*8);
    int tid = threadIdx.x;
    int pbase = blockIdx.x * 64;
    int b = pbase >> 13;
    #pragma unroll
    for (int it = 0; it < 4; ++it) {
        int flat = it*1024 + tid*4;
        int p = pbase + (flat >> 6);
        int m = flat & 63;
        int g = m >> 3;
        float sv = stats[b*16 + g*2 + 0];
        float qv = stats[b*16 + g*2 + 1];
        float mean = sv * invcnt;
        float var  = fmaf(-mean, mean, qv * invcnt);
        float rstd = rsqrtf(var + EPSV);
        u16x4 v = *(const u16x4*)&z3[p*64 + m];
        float r[4];
        #pragma unroll
        for (int j = 0; j < 4; ++j) {
            float aa = g3[m+j] * rstd;
            float z  = fmaf(aa, bf2f(v[j]) - mean, b3[m+j]);
            r[j] = (z >= 0.f) ? z : SLOPEV * z;
        }
        f32x4 o4 = {r[0], r[1], r[2], r[3]};
        *(f32x4*)&out[p*64 + m] = o4;
    }
}

// ---------------------------------------------------------------- launch
extern "C" void kernel_launch(void* const* d_in, const int* in_sizes, int n_in,
                              void* d_out, int out_size, void* d_ws, size_t ws_size,
                              hipStream_t stream)
{
    const float* sig = (const float*)d_in[0];
    const void*  edg = d_in[1];
    const float* ef  = (const float*)d_in[2];
    const float* W1  = (const float*)d_in[3];
    const float* g1  = (const float*)d_in[4];
    const float* b1  = (const float*)d_in[5];
    const float* W2  = (const float*)d_in[6];
    const float* g2  = (const float*)d_in[7];
    const float* b2  = (const float*)d_in[8];
    const float* W3  = (const float*)d_in[9];
    const float* g3  = (const float*)d_in[10];
    const float* b3  = (const float*)d_in[11];
    float* out = (float*)d_out;
    float* ws  = (float*)d_ws;
    u16*   yb  = (u16*)(ws + WS_YB);
    u16*   mxb = (u16*)(ws + WS_MX);
    u16*   mnb = (u16*)(ws + WS_MN);

    k_mm<0><<<NPTS/64, 256, 0, stream>>>(sig, nullptr, W1, nullptr, 0.f,
                                         nullptr, nullptr, yb, nullptr, ws);
    k_edge<<<NPTS/EPB, 512, 0, stream>>>(yb, edg, ef, W1, mxb, mnb,
                                         ws + WS_STATS1);
    k_mm<1><<<NPTS/64, 256, 0, stream>>>(mxb, mnb, W2, ws + WS_STATS1,
                                         1.f/(float)(NPB*KNB*8), g1, b1,
                                         yb, ws + WS_STATS2, nullptr);
    k_mm<2><<<NPTS/64, 256, 0, stream>>>(yb, nullptr, W3, ws + WS_STATS2,
                                         1.f/(float)(NPB*8), g2, b2,
                                         mxb, ws + WS_STATS3, nullptr);
    k_out<<<NPTS/64, 256, 0, stream>>>(mxb, ws + WS_STATS3, g3, b3, out);
}

// Round 16
// 55.333 us; speedup vs baseline: 1.1067x; 1.1067x over previous
//
#include <hip/hip_runtime.h>

#define NB    4
#define NPB   8192
#define NPTS  (NB*NPB)      // 32768
#define KNB   32
#define CH    64
#define W1C   67
#define EPSV  1e-5f
#define SLOPEV 0.1f

typedef float f32x2 __attribute__((ext_vector_type(2)));
typedef float f32x4 __attribute__((ext_vector_type(4)));
typedef short bf16x8 __attribute__((ext_vector_type(8)));
typedef unsigned short u16;
typedef u16 u16x4 __attribute__((ext_vector_type(4)));
typedef u16 u16x8 __attribute__((ext_vector_type(8)));

// workspace layout (float offsets) — all big buffers bf16
#define WS_STATS1 0
#define WS_STATS2 64
#define WS_STATS3 128
#define WS_YB     256                        // bf16 Y, later bf16 z2pre
#define WS_MX     (WS_YB + NPTS*CH/2)        // bf16 Mx, later bf16 z3pre
#define WS_MN     (WS_MX + NPTS*CH/2)        // bf16 Mn

#define LDPW 68                // Wl row stride (u16): 4-way max alias
#define SEDS (KNB*4 + 4)       // per-point float stride in sed
#define EPB  64                // edge points per block

__device__ __forceinline__ u16 f2bf(float f) {
    unsigned u = __float_as_uint(f);
    u += 0x7fff + ((u >> 16) & 1);          // round-nearest-even
    return (u16)(u >> 16);
}
__device__ __forceinline__ float bf2f(u16 h) {
    return __uint_as_float(((unsigned)h) << 16);
}
__device__ __forceinline__ bool probe_is32(const int* e_i32, int tid) {
    int found = 0;
    #pragma unroll
    for (int i = 0; i < 8; ++i)
        found |= (e_i32[(tid*8 + i)*2 + 1] != 0);
    return (__ballot(found) != 0ull);
}

// ---------------------------------------------------------------- MFMA matmul family (64 pts/block)
// MODE 0: YB(bf16) = sig * W1s^T   (+ stats zeroing in block 0)
// MODE 1: Z2B(bf16) = GN1(lrelu,max/min-select) * W2^T; stats2
// MODE 2: Z3B(bf16) = GN2(lrelu) * W3^T; stats3
template<int MODE>
__global__ __launch_bounds__(256) void k_mm(
    const void* __restrict__ X0, const void* __restrict__ X1,
    const float* __restrict__ Wg,
    const float* __restrict__ statsIn, float invcnt,
    const float* __restrict__ gm, const float* __restrict__ bt,
    u16* __restrict__ Out, float* __restrict__ statsOut,
    float* __restrict__ zeroStats)
{
    __shared__ u16 Wl[64*LDPW];
    __shared__ __align__(16) float affA[64];
    __shared__ __align__(16) float affB[64];
    __shared__ float lacc[16];
    int tid = threadIdx.x;
    int pbase = blockIdx.x * 64;
    int b = pbase >> 13;

    if (MODE == 0 && blockIdx.x == 0 && tid < 192) zeroStats[tid] = 0.f;
    if (MODE != 0) {
        if (tid < 64) {
            int g = tid >> 3;
            float sv = statsIn[b*16 + g*2 + 0];
            float qv = statsIn[b*16 + g*2 + 1];
            float mean = sv * invcnt;
            float var  = fmaf(-mean, mean, qv * invcnt);
            float rstd = rsqrtf(var + EPSV);
            float a = gm[tid] * rstd;
            affA[tid] = a;
            affB[tid] = fmaf(-mean, a, bt[tid]);
        }
        if (tid < 16) lacc[tid] = 0.f;
    }
    {
        const int wstride = (MODE == 0) ? W1C : 64;
        #pragma unroll
        for (int i = 0; i < 16; ++i) {
            int e = tid + 256*i;
            int o = e >> 6, m = e & 63;
            Wl[o*LDPW + m] = f2bf(Wg[o*wstride + m]);
        }
    }
    __syncthreads();

    int l = tid & 63, w = tid >> 6;
    int lr = l & 15, lk = l >> 4;
    int row = pbase + w*16 + lr;

    bf16x8 af[2];
    #pragma unroll
    for (int kh = 0; kh < 2; ++kh) {
        int m0 = kh*32 + lk*8;
        bf16x8 h;
        if (MODE == 0) {
            f32x4 a0 = *(const f32x4*)&((const float*)X0)[row*64 + m0];
            f32x4 a1 = *(const f32x4*)&((const float*)X0)[row*64 + m0 + 4];
            #pragma unroll
            for (int j = 0; j < 4; ++j) {
                h[j]   = (short)f2bf(a0[j]);
                h[4+j] = (short)f2bf(a1[j]);
            }
        } else {
            float aA[8], aB[8];
            *(f32x4*)&aA[0] = *(const f32x4*)&affA[m0];
            *(f32x4*)&aA[4] = *(const f32x4*)&affA[m0+4];
            *(f32x4*)&aB[0] = *(const f32x4*)&affB[m0];
            *(f32x4*)&aB[4] = *(const f32x4*)&affB[m0+4];
            u16x8 vx = *(const u16x8*)&((const u16*)X0)[row*64 + m0];
            if (MODE == 1) {
                u16x8 vn = *(const u16x8*)&((const u16*)X1)[row*64 + m0];
                #pragma unroll
                for (int j = 0; j < 8; ++j) {
                    float a = aA[j];
                    float x = (a < 0.f) ? bf2f(vn[j]) : bf2f(vx[j]);
                    float z = fmaf(a, x, aB[j]);
                    z = (z >= 0.f) ? z : SLOPEV * z;
                    h[j] = (short)f2bf(z);
                }
            } else {
                #pragma unroll
                for (int j = 0; j < 8; ++j) {
                    float z = fmaf(aA[j], bf2f(vx[j]), aB[j]);
                    z = (z >= 0.f) ? z : SLOPEV * z;
                    h[j] = (short)f2bf(z);
                }
            }
        }
        af[kh] = h;
    }

    bf16x8 bw[4][2];
    #pragma unroll
    for (int ot = 0; ot < 4; ++ot)
        #pragma unroll
        for (int kh = 0; kh < 2; ++kh)
            bw[ot][kh] = *(const bf16x8*)&Wl[(ot*16 + lr)*LDPW + kh*32 + lk*8];

    f32x4 acc[4];
    #pragma unroll
    for (int ot = 0; ot < 4; ++ot) {
        f32x4 c = {0.f, 0.f, 0.f, 0.f};
        c = __builtin_amdgcn_mfma_f32_16x16x32_bf16(af[0], bw[ot][0], c, 0, 0, 0);
        c = __builtin_amdgcn_mfma_f32_16x16x32_bf16(af[1], bw[ot][1], c, 0, 0, 0);
        acc[ot] = c;
    }

    #pragma unroll
    for (int ot = 0; ot < 4; ++ot)
        #pragma unroll
        for (int r = 0; r < 4; ++r) {
            int p = pbase + w*16 + lk*4 + r;
            int o = ot*16 + lr;
            Out[p*64 + o] = f2bf(acc[ot][r]);
        }

    if (MODE != 0) {
        #pragma unroll
        for (int ot = 0; ot < 4; ++ot) {
            float s = 0.f, ss = 0.f;
            #pragma unroll
            for (int r = 0; r < 4; ++r) {
                float v = acc[ot][r];
                s += v;
                ss = fmaf(v, v, ss);
            }
            s += __shfl_xor(s, 16, 64);  ss += __shfl_xor(ss, 16, 64);
            s += __shfl_xor(s, 32, 64);  ss += __shfl_xor(ss, 32, 64);
            s += __shfl_xor(s, 1, 64);   ss += __shfl_xor(ss, 1, 64);
            s += __shfl_xor(s, 2, 64);   ss += __shfl_xor(ss, 2, 64);
            s += __shfl_xor(s, 4, 64);   ss += __shfl_xor(ss, 4, 64);
            if ((l & 7) == 0 && l < 16) {
                int g = ot*2 + (l >> 3);
                atomicAdd(&lacc[g*2 + 0], s);
                atomicAdd(&lacc[g*2 + 1], ss);
            }
        }
        __syncthreads();
        if (tid < 16)
            atomicAdd(&statsOut[b*16 + tid], lacc[tid]);
    }
}

// ---------------------------------------------------------------- edge pass (512 thr, 64 pts/block, 2-stage SW pipeline)
__global__ __launch_bounds__(512) void k_edge(
    const u16* __restrict__ Yb, const void* __restrict__ edg,
    const float* __restrict__ ef, const float* __restrict__ W1,
    u16* __restrict__ Mx, u16* __restrict__ Mn, float* __restrict__ stats1)
{
    __shared__ float sed[EPB*SEDS];
    __shared__ float lacc[16];
    int tid = threadIdx.x;
    if (tid < 16) lacc[tid] = 0.f;

    bool is32 = probe_is32((const int*)edg, tid);
    {
        const int* e32 = (const int*)edg;
        const long long* e64 = (const long long*)edg;
        int ebase = blockIdx.x * (EPB*KNB);
        #pragma unroll
        for (int i = 0; i < 4; ++i) {
            int idx = tid + i*512;
            int gi  = ebase + idx;
            int e   = is32 ? __builtin_nontemporal_load(e32 + gi)
                           : (int)__builtin_nontemporal_load(e64 + gi);
            int pt = idx >> 5, k = idx & 31;
            float* d = &sed[pt*SEDS + k*4];
            d[0] = __builtin_nontemporal_load(ef + gi*3 + 0);
            d[1] = __builtin_nontemporal_load(ef + gi*3 + 1);
            d[2] = __builtin_nontemporal_load(ef + gi*3 + 2);
            d[3] = __int_as_float(e << 7);
        }
    }

    int lane = tid & 63, wv = tid >> 6;
    int il = lane & 7;
    int g8 = lane >> 3;
    int lpt = wv*8 + g8;
    int p = blockIdx.x * EPB + lpt;

    f32x2 w0[4], w1[4], w2[4];
    #pragma unroll
    for (int jj = 0; jj < 4; ++jj) {
        int ch = il*8 + jj*2;
        w0[jj] = (f32x2){W1[ch*W1C + 64], W1[(ch+1)*W1C + 64]};
        w1[jj] = (f32x2){W1[ch*W1C + 65], W1[(ch+1)*W1C + 65]};
        w2[jj] = (f32x2){W1[ch*W1C + 66], W1[(ch+1)*W1C + 66]};
    }
    f32x2 yp[4], mx[4], mn[4];
    u16x8 yh = *(const u16x8*)&Yb[p*64 + il*8];
    #pragma unroll
    for (int jj = 0; jj < 4; ++jj) {
        yp[jj] = (f32x2){bf2f(yh[jj*2]), bf2f(yh[jj*2+1])};
        mx[jj] = (f32x2){-3.4e38f, -3.4e38f};
        mn[jj] = (f32x2){ 3.4e38f,  3.4e38f};
    }
    f32x2 s2 = {0.f, 0.f}, ss2 = {0.f, 0.f};
    __syncthreads();

    const char* Ybase = (const char*)Yb + il*16;
    const float* sp = &sed[lpt*SEDS];

    // 2-stage software pipeline: stage k+1's metadata+gather issue before k's math
    f32x4 m4 = *(const f32x4*)(sp);
    u16x8 q = *(const u16x8*)(Ybase + __float_as_int(m4[3]));
    #pragma unroll 4
    for (int k = 0; k < KNB; ++k) {
        f32x4 m4n;
        u16x8 qn;
        if (k < KNB-1) {
            m4n = *(const f32x4*)(sp + (k+1)*4);
            qn  = *(const u16x8*)(Ybase + __float_as_int(m4n[3]));
        }
        f32x2 c0v = m4[0], c1v = m4[1], c2v = m4[2];
        #pragma unroll
        for (int jj = 0; jj < 4; ++jj) {
            f32x2 qq = {bf2f(q[jj*2]), bf2f(q[jj*2+1])};
            f32x2 t = qq - yp[jj];
            t = __builtin_elementwise_fma(c0v, w0[jj], t);
            t = __builtin_elementwise_fma(c1v, w1[jj], t);
            t = __builtin_elementwise_fma(c2v, w2[jj], t);
            mx[jj] = __builtin_elementwise_max(mx[jj], t);
            mn[jj] = __builtin_elementwise_min(mn[jj], t);
            s2 += t;
            ss2 = __builtin_elementwise_fma(t, t, ss2);
        }
        m4 = m4n;
        q  = qn;
    }

    u16x8 hx, hn;
    #pragma unroll
    for (int jj = 0; jj < 4; ++jj) {
        hx[jj*2] = f2bf(mx[jj].x); hx[jj*2+1] = f2bf(mx[jj].y);
        hn[jj*2] = f2bf(mn[jj].x); hn[jj*2+1] = f2bf(mn[jj].y);
    }
    __builtin_nontemporal_store(hx, (u16x8*)(Mx + p*64 + il*8));
    __builtin_nontemporal_store(hn, (u16x8*)(Mn + p*64 + il*8));

    float s  = s2.x + s2.y;
    float ss = ss2.x + ss2.y;
    s += __shfl_xor(s,  8, 64);  ss += __shfl_xor(ss,  8, 64);
    s += __shfl_xor(s, 16, 64);  ss += __shfl_xor(ss, 16, 64);
    s += __shfl_xor(s, 32, 64);  ss += __shfl_xor(ss, 32, 64);
    if (lane < 8) {
        atomicAdd(&lacc[lane*2 + 0], s);
        atomicAdd(&lacc[lane*2 + 1], ss);
    }
    __syncthreads();
    if (tid < 16) {
        int b = (blockIdx.x * EPB) >> 13;
        atomicAdd(&stats1[b*16 + tid], lacc[tid]);
    }
}

// ---------------------------------------------------------------- final GN + lrelu -> out (64 pts/block)
__global__ __launch_bounds__(256) void k_out(
    const u16* __restrict__ z3, const float* __restrict__ stats,
    const float* __restrict__ g3, const float* __restrict__ b3,
    float* __restrict__ out)
{
    const float invcnt = 1.f/(float)(NPB*8);
    int tid = threadIdx.x;
    int pbase = blockIdx.x * 64;
    int b = pbase >> 13;
    #pragma unroll
    for (int it = 0; it < 4; ++it) {
        int flat = it*1024 + tid*4;
        int p = pbase + (flat >> 6);
        int m = flat & 63;
        int g = m >> 3;
        float sv = stats[b*16 + g*2 + 0];
        float qv = stats[b*16 + g*2 + 1];
        float mean = sv * invcnt;
        float var  = fmaf(-mean, mean, qv * invcnt);
        float rstd = rsqrtf(var + EPSV);
        u16x4 v = *(const u16x4*)&z3[p*64 + m];
        float r[4];
        #pragma unroll
        for (int j = 0; j < 4; ++j) {
            float aa = g3[m+j] * rstd;
            float z  = fmaf(aa, bf2f(v[j]) - mean, b3[m+j]);
            r[j] = (z >= 0.f) ? z : SLOPEV * z;
        }
        f32x4 o4 = {r[0], r[1], r[2], r[3]};
        *(f32x4*)&out[p*64 + m] = o4;
    }
}

// ---------------------------------------------------------------- launch
extern "C" void kernel_launch(void* const* d_in, const int* in_sizes, int n_in,
                              void* d_out, int out_size, void* d_ws, size_t ws_size,
                              hipStream_t stream)
{
    const float* sig = (const float*)d_in[0];
    const void*  edg = d_in[1];
    const float* ef  = (const float*)d_in[2];
    const float* W1  = (const float*)d_in[3];
    const float* g1  = (const float*)d_in[4];
    const float* b1  = (const float*)d_in[5];
    const float* W2  = (const float*)d_in[6];
    const float* g2  = (const float*)d_in[7];
    const float* b2  = (const float*)d_in[8];
    const float* W3  = (const float*)d_in[9];
    const float* g3  = (const float*)d_in[10];
    const float* b3  = (const float*)d_in[11];
    float* out = (float*)d_out;
    float* ws  = (float*)d_ws;
    u16*   yb  = (u16*)(ws + WS_YB);
    u16*   mxb = (u16*)(ws + WS_MX);
    u16*   mnb = (u16*)(ws + WS_MN);

    k_mm<0><<<NPTS/64, 256, 0, stream>>>(sig, nullptr, W1, nullptr, 0.f,
                                         nullptr, nullptr, yb, nullptr, ws);
    k_edge<<<NPTS/EPB, 512, 0, stream>>>(yb, edg, ef, W1, mxb, mnb,
                                         ws + WS_STATS1);
    k_mm<1><<<NPTS/64, 256, 0, stream>>>(mxb, mnb, W2, ws + WS_STATS1,
                                         1.f/(float)(NPB*KNB*8), g1, b1,
                                         yb, ws + WS_STATS2, nullptr);
    k_mm<2><<<NPTS/64, 256, 0, stream>>>(yb, nullptr, W3, ws + WS_STATS2,
                                         1.f/(float)(NPB*8), g2, b2,
                                         mxb, ws + WS_STATS3, nullptr);
    k_out<<<NPTS/64, 256, 0, stream>>>(mxb, ws + WS_STATS3, g3, b3, out);
}